// Round 2
// baseline (132.383 us; speedup 1.0000x reference)
//
#include <hip/hip_runtime.h>
#include <hip/hip_bf16.h>
#include <stdint.h>

// HashedLinear: C[1024][4096] = x[1024][4096] @ w[indx[4096][4096]] + b
#define M_DIM 1024
#define K_DIM 4096
#define N_DIM 4096
#define NW    65536

typedef __bf16 bf16x8 __attribute__((ext_vector_type(8)));
typedef float  f32x4  __attribute__((ext_vector_type(4)));

// float -> bf16 round-to-nearest-even (bit trick; inputs are normal floats)
__device__ __forceinline__ unsigned short f2bf(float f) {
  unsigned u = __float_as_uint(f);
  u += 0x7fffu + ((u >> 16) & 1u);
  return (unsigned short)(u >> 16);
}

__device__ __forceinline__ void load_lds16(const void* g, void* l) {
  __builtin_amdgcn_global_load_lds((const __attribute__((address_space(1))) void*)g,
                                   (__attribute__((address_space(3))) void*)l,
                                   16, 0, 0);
}

// ---- kernel 1: convert x and w to bf16 (stored as ushort) ----
__global__ void prep_kernel(const float* __restrict__ x, const float* __restrict__ w,
                            unsigned short* __restrict__ xb, unsigned short* __restrict__ wb) {
  const int XQ = M_DIM * K_DIM / 4;   // float4 quads of x
  const int WQ = NW / 4;              // float4 quads of w
  int i = blockIdx.x * blockDim.x + threadIdx.x;
  if (i < XQ) {
    float4 v = reinterpret_cast<const float4*>(x)[i];
    ushort4 o;
    o.x = f2bf(v.x); o.y = f2bf(v.y); o.z = f2bf(v.z); o.w = f2bf(v.w);
    reinterpret_cast<ushort4*>(xb)[i] = o;
  } else if (i < XQ + WQ) {
    int j = i - XQ;
    float4 v = reinterpret_cast<const float4*>(w)[j];
    ushort4 o;
    o.x = f2bf(v.x); o.y = f2bf(v.y); o.z = f2bf(v.z); o.w = f2bf(v.w);
    reinterpret_cast<ushort4*>(wb)[j] = o;
  }
}

// ---- kernel 2: gather + transpose:  Bt[n][k] = wb[indx[k][n]]  (bf16) ----
// 64x64 tile per block; coalesced indx reads, LDS transpose, coalesced Bt writes.
__global__ void gather_kernel(const int* __restrict__ indx,
                              const unsigned short* __restrict__ wb,
                              unsigned short* __restrict__ Bt) {
  __shared__ unsigned short tile[64][68];  // stride 68 elems (136B): 2-way bank aliasing only
  int t = threadIdx.x;
  int k0 = blockIdx.x * 64, n0 = blockIdx.y * 64;
#pragma unroll
  for (int it = 0; it < 4; ++it) {
    int r  = (t >> 4) + it * 16;  // k-row within tile
    int cq = t & 15;              // int4 column group
    int4 id = *reinterpret_cast<const int4*>(indx + (size_t)(k0 + r) * N_DIM + n0 + cq * 4);
    tile[r][cq * 4 + 0] = wb[id.x];
    tile[r][cq * 4 + 1] = wb[id.y];
    tile[r][cq * 4 + 2] = wb[id.z];
    tile[r][cq * 4 + 3] = wb[id.w];
  }
  __syncthreads();
  // write phase: full 64 n-rows x 64 k-cols.  nn spans [0,64), kq spans 16 quads = 64 k.
#pragma unroll
  for (int it = 0; it < 4; ++it) {
    int nn = (t >> 4) + it * 16;  // n within tile
    int kq = t & 15;              // k quad (16 quads = 64 k values)
    ushort4 o;
    o.x = tile[kq * 4 + 0][nn];
    o.y = tile[kq * 4 + 1][nn];
    o.z = tile[kq * 4 + 2][nn];
    o.w = tile[kq * 4 + 3][nn];
    *reinterpret_cast<ushort4*>(Bt + (size_t)(n0 + nn) * K_DIM + k0 + kq * 4) = o;
  }
}

// ---- kernel 3: bf16 MFMA GEMM, B^T input, m97-style single-buffer structure ----
#define BM 128
#define BN 64
#define BK 32

__global__ __launch_bounds__(256)
void gemm_kernel(const unsigned short* __restrict__ A,   // x bf16 [M][K]
                 const unsigned short* __restrict__ Bt,  // B^T bf16 [N][K]
                 const float* __restrict__ bias,
                 float* __restrict__ C) {                // [M][N] f32
  __shared__ unsigned short As[BM][BK];  // 8 KB, 64B rows
  __shared__ unsigned short Bs[BN][BK];  // 4 KB

  int t = threadIdx.x;
  int lane = t & 63, wid = t >> 6;
  int wm = wid >> 1, wn = wid & 1;       // 2x2 wave grid; wave tile 64x32
  int m0 = blockIdx.x * BM, n0 = blockIdx.y * BN;

  const unsigned short* Ag = A  + (size_t)m0 * K_DIM;
  const unsigned short* Bg = Bt + (size_t)n0 * K_DIM;

  f32x4 acc[4][2];
#pragma unroll
  for (int i = 0; i < 4; ++i)
#pragma unroll
    for (int j = 0; j < 2; ++j)
      acc[i][j] = (f32x4){0.f, 0.f, 0.f, 0.f};

  int fr = lane & 15, ko = (lane >> 4) * 8;  // MFMA fragment row / k-offset

  for (int kt = 0; kt < K_DIM / BK; ++kt) {
    int kb = kt * BK;
    {
      // A tile: 128 rows x 64B = 512 x 16B chunks; 2 per thread
      int c = t;
      load_lds16(Ag + (size_t)(c >> 2) * K_DIM + kb + (c & 3) * 8,
                 (char*)&As[0][0] + c * 16);
      c = t + 256;
      load_lds16(Ag + (size_t)(c >> 2) * K_DIM + kb + (c & 3) * 8,
                 (char*)&As[0][0] + c * 16);
      // B tile: 64 rows x 64B = 256 x 16B chunks; 1 per thread
      c = t;
      load_lds16(Bg + (size_t)(c >> 2) * K_DIM + kb + (c & 3) * 8,
                 (char*)&Bs[0][0] + c * 16);
    }
    __syncthreads();  // compiler emits vmcnt(0) drain before barrier

    bf16x8 af[4], bfr[2];
#pragma unroll
    for (int mi = 0; mi < 4; ++mi)
      af[mi] = *reinterpret_cast<const bf16x8*>(&As[wm * 64 + mi * 16 + fr][ko]);
#pragma unroll
    for (int ni = 0; ni < 2; ++ni)
      bfr[ni] = *reinterpret_cast<const bf16x8*>(&Bs[wn * 32 + ni * 16 + fr][ko]);
#pragma unroll
    for (int mi = 0; mi < 4; ++mi)
#pragma unroll
      for (int ni = 0; ni < 2; ++ni)
        acc[mi][ni] = __builtin_amdgcn_mfma_f32_16x16x32_bf16(af[mi], bfr[ni], acc[mi][ni], 0, 0, 0);
    __syncthreads();
  }

  // epilogue: C/D layout col = lane&15, row = (lane>>4)*4 + j  (m89-verified)
  int fq = lane >> 4;
#pragma unroll
  for (int ni = 0; ni < 2; ++ni) {
    int gc = n0 + wn * 32 + ni * 16 + fr;
    float bv = bias[gc];
#pragma unroll
    for (int mi = 0; mi < 4; ++mi) {
      int gr = m0 + wm * 64 + mi * 16 + fq * 4;
#pragma unroll
      for (int j = 0; j < 4; ++j)
        C[(size_t)(gr + j) * N_DIM + gc] = acc[mi][ni][j] + bv;
    }
  }
}

extern "C" void kernel_launch(void* const* d_in, const int* in_sizes, int n_in,
                              void* d_out, int out_size, void* d_ws, size_t ws_size,
                              hipStream_t stream) {
  const float* x    = (const float*)d_in[0];
  const float* w    = (const float*)d_in[1];
  const float* b    = (const float*)d_in[2];
  const int*   indx = (const int*)d_in[3];
  float* out = (float*)d_out;

  // workspace layout: xb (8 MB) | wb (128 KB) | Bt (32 MB)  => needs ~40.2 MB
  unsigned short* xb = (unsigned short*)d_ws;
  unsigned short* wb = xb + (size_t)M_DIM * K_DIM;
  unsigned short* Bt = wb + NW;

  int prep_total = (M_DIM * K_DIM + NW) / 4;
  prep_kernel<<<(prep_total + 255) / 256, 256, 0, stream>>>(x, w, xb, wb);
  gather_kernel<<<dim3(K_DIM / 64, N_DIM / 64), 256, 0, stream>>>(indx, wb, Bt);
  gemm_kernel<<<dim3(M_DIM / BM, N_DIM / BN), 256, 0, stream>>>(xb, Bt, b, out);
}

// Round 3
// 78.094 us; speedup vs baseline: 1.6952x; 1.6952x over previous
//
#include <hip/hip_runtime.h>
#include <hip/hip_bf16.h>
#include <stdint.h>

// HashedLinear: C[1024][4096] = x[1024][4096] @ w[indx[4096][4096]] + b
#define M_DIM 1024
#define K_DIM 4096
#define N_DIM 4096
#define NW    65536

typedef __bf16 bf16x8 __attribute__((ext_vector_type(8)));
typedef float  f32x4  __attribute__((ext_vector_type(4)));

// float -> bf16 round-to-nearest-even (bit trick; inputs are normal floats)
__device__ __forceinline__ unsigned short f2bf(float f) {
  unsigned u = __float_as_uint(f);
  u += 0x7fffu + ((u >> 16) & 1u);
  return (unsigned short)(u >> 16);
}

__device__ __forceinline__ void load_lds16(const void* g, void* l) {
  __builtin_amdgcn_global_load_lds((const __attribute__((address_space(1))) void*)g,
                                   (__attribute__((address_space(3))) void*)l,
                                   16, 0, 0);
}

// ---- kernel 1: convert x and w to bf16 (stored as ushort) ----
__global__ void prep_kernel(const float* __restrict__ x, const float* __restrict__ w,
                            unsigned short* __restrict__ xb, unsigned short* __restrict__ wb) {
  const int XQ = M_DIM * K_DIM / 4;
  const int WQ = NW / 4;
  int i = blockIdx.x * blockDim.x + threadIdx.x;
  if (i < XQ) {
    float4 v = reinterpret_cast<const float4*>(x)[i];
    ushort4 o;
    o.x = f2bf(v.x); o.y = f2bf(v.y); o.z = f2bf(v.z); o.w = f2bf(v.w);
    reinterpret_cast<ushort4*>(xb)[i] = o;
  } else if (i < XQ + WQ) {
    int j = i - XQ;
    float4 v = reinterpret_cast<const float4*>(w)[j];
    ushort4 o;
    o.x = f2bf(v.x); o.y = f2bf(v.y); o.z = f2bf(v.z); o.w = f2bf(v.w);
    reinterpret_cast<ushort4*>(wb)[j] = o;
  }
}

// ---- kernel 2: gather + transpose with the WHOLE pool staged in LDS ----
// 256 blocks x 1024 threads, 1 block/CU (LDS 136.5 KB). 16 tiles of 64x64 per
// block. Gathers become ds_read_u16 from the 128 KB LDS pool instead of L1/L2
// transactions; kernel is then bound by indx (64 MB) + Bt (32 MB) streaming.
__global__ __launch_bounds__(1024)
void gather_kernel(const int* __restrict__ indx,
                   const unsigned short* __restrict__ wb,
                   unsigned short* __restrict__ Bt) {
  __shared__ unsigned short pool[NW];        // 128 KB
  __shared__ unsigned short tile[64][68];    // 8.5 KB, stride 136B de-aligns banks
  int t = threadIdx.x;

  // stage full bf16 pool into LDS (8 x uint4 per thread = 128 B/thread)
  {
    const uint4* src = reinterpret_cast<const uint4*>(wb);
    uint4* dst = reinterpret_cast<uint4*>(pool);
#pragma unroll
    for (int i = 0; i < 8; ++i) dst[t + i * 1024] = src[t + i * 1024];
  }

  int r  = t >> 4, cq = t & 15;   // load-phase coords (k-row, n-quad)
  int nn = t >> 4, kq = t & 15;   // write-phase coords (n-row, k-quad)
  int base_tid = blockIdx.x * 16;

  // prefetch first tile's indices (independent of pool staging)
  int4 id;
  {
    int k0 = ((base_tid >> 6) << 6), n0 = ((base_tid & 63) << 6);
    id = *reinterpret_cast<const int4*>(indx + (size_t)(k0 + r) * N_DIM + n0 + cq * 4);
  }
  __syncthreads();  // pool ready

  for (int it = 0; it < 16; ++it) {
    int tid = base_tid + it;
    int k0 = ((tid >> 6) << 6), n0 = ((tid & 63) << 6);

    // prefetch next tile's indx while gathering this one
    int4 idn = id;
    if (it < 15) {
      int tid2 = tid + 1;
      int k02 = ((tid2 >> 6) << 6), n02 = ((tid2 & 63) << 6);
      idn = *reinterpret_cast<const int4*>(indx + (size_t)(k02 + r) * N_DIM + n02 + cq * 4);
    }

    tile[r][cq * 4 + 0] = pool[id.x];
    tile[r][cq * 4 + 1] = pool[id.y];
    tile[r][cq * 4 + 2] = pool[id.z];
    tile[r][cq * 4 + 3] = pool[id.w];
    __syncthreads();

    ushort4 o;
    o.x = tile[kq * 4 + 0][nn];
    o.y = tile[kq * 4 + 1][nn];
    o.z = tile[kq * 4 + 2][nn];
    o.w = tile[kq * 4 + 3][nn];
    *reinterpret_cast<ushort4*>(Bt + (size_t)(n0 + nn) * K_DIM + k0 + kq * 4) = o;
    __syncthreads();  // protect tile before next iteration overwrites

    id = idn;
  }
}

// ---- kernel 3: bf16 MFMA GEMM, BK=64, XOR-swizzled LDS, XCD-swizzled grid ----
#define BM 128
#define BN 64
#define BK 64

__global__ __launch_bounds__(256)
void gemm_kernel(const unsigned short* __restrict__ A,   // x bf16 [M][K]
                 const unsigned short* __restrict__ Bt,  // B^T bf16 [N][K]
                 const float* __restrict__ bias,
                 float* __restrict__ C) {                // [M][N] f32
  __shared__ unsigned short As[BM * BK];  // 16 KB, 128B rows
  __shared__ unsigned short Bs[BN * BK];  // 8 KB

  int t = threadIdx.x;
  int lane = t & 63, wid = t >> 6;
  int wm = wid >> 1, wn = wid & 1;        // 2x2 wave grid; wave tile 64x32

  // XCD swizzle: nwg=512 (512%8==0): XCD x gets 64 consecutive logical blocks
  // => 8 consecutive Bt panels (4 MB = one XCD L2) resident per XCD.
  int bid = blockIdx.x;
  int swz = (bid & 7) * 64 + (bid >> 3);
  int bx = swz & 7, by = swz >> 3;        // bx: M-tile (8), by: N-tile (64)
  int m0 = bx * BM, n0 = by * BN;

  const unsigned short* Ag = A  + (size_t)m0 * K_DIM;
  const unsigned short* Bg = Bt + (size_t)n0 * K_DIM;

  f32x4 acc[4][2];
#pragma unroll
  for (int i = 0; i < 4; ++i)
#pragma unroll
    for (int j = 0; j < 2; ++j)
      acc[i][j] = (f32x4){0.f, 0.f, 0.f, 0.f};

  int fr = lane & 15, hc = lane >> 4;     // frag row, k-half-chunk

  for (int kb = 0; kb < K_DIM; kb += BK) {
    // Staging: LDS linear (global_load_lds requires it); swizzle applied by
    // permuting the GLOBAL source 16B-chunk: slot s holds chunk s^(r&7).
    // A: 128 rows x 8 chunks = 1024; B: 64 x 8 = 512. 256 threads.
#pragma unroll
    for (int i = 0; i < 4; ++i) {
      int c = t + i * 256;
      int r = c >> 3, s = c & 7;
      load_lds16(Ag + (size_t)r * K_DIM + kb + ((s ^ (r & 7)) << 3),
                 (char*)As + c * 16);
    }
#pragma unroll
    for (int i = 0; i < 2; ++i) {
      int c = t + i * 256;
      int r = c >> 3, s = c & 7;
      load_lds16(Bg + (size_t)r * K_DIM + kb + ((s ^ (r & 7)) << 3),
                 (char*)Bs + c * 16);
    }
    __syncthreads();

#pragma unroll
    for (int kk = 0; kk < 2; ++kk) {
      bf16x8 af[4], bfv[2];
#pragma unroll
      for (int mi = 0; mi < 4; ++mi) {
        int row = wm * 64 + mi * 16 + fr;
        int q = (hc + kk * 4) ^ (row & 7);   // logical chunk ^ row swizzle
        af[mi] = *reinterpret_cast<const bf16x8*>((char*)As + row * 128 + q * 16);
      }
#pragma unroll
      for (int ni = 0; ni < 2; ++ni) {
        int row = wn * 32 + ni * 16 + fr;
        int q = (hc + kk * 4) ^ (row & 7);
        bfv[ni] = *reinterpret_cast<const bf16x8*>((char*)Bs + row * 128 + q * 16);
      }
#pragma unroll
      for (int mi = 0; mi < 4; ++mi)
#pragma unroll
        for (int ni = 0; ni < 2; ++ni)
          acc[mi][ni] = __builtin_amdgcn_mfma_f32_16x16x32_bf16(af[mi], bfv[ni], acc[mi][ni], 0, 0, 0);
    }
    __syncthreads();
  }

  // epilogue: C/D layout col = lane&15, row = (lane>>4)*4 + j  (m89-verified)
  int fq = lane >> 4;
#pragma unroll
  for (int ni = 0; ni < 2; ++ni) {
    int gc = n0 + wn * 32 + ni * 16 + fr;
    float bv = bias[gc];
#pragma unroll
    for (int mi = 0; mi < 4; ++mi) {
      int gr = m0 + wm * 64 + mi * 16 + fq * 4;
#pragma unroll
      for (int j = 0; j < 4; ++j)
        C[(size_t)(gr + j) * N_DIM + gc] = acc[mi][ni][j] + bv;
    }
  }
}

extern "C" void kernel_launch(void* const* d_in, const int* in_sizes, int n_in,
                              void* d_out, int out_size, void* d_ws, size_t ws_size,
                              hipStream_t stream) {
  const float* x    = (const float*)d_in[0];
  const float* w    = (const float*)d_in[1];
  const float* b    = (const float*)d_in[2];
  const int*   indx = (const int*)d_in[3];
  float* out = (float*)d_out;

  // workspace: xb (8 MB) | wb (128 KB) | Bt (32 MB)
  unsigned short* xb = (unsigned short*)d_ws;
  unsigned short* wb = xb + (size_t)M_DIM * K_DIM;
  unsigned short* Bt = wb + NW;

  int prep_total = (M_DIM * K_DIM + NW) / 4;
  prep_kernel<<<(prep_total + 255) / 256, 256, 0, stream>>>(x, w, xb, wb);
  gather_kernel<<<256, 1024, 0, stream>>>(indx, wb, Bt);
  gemm_kernel<<<512, 256, 0, stream>>>(xb, Bt, b, out);
}